// Round 5
// baseline (505.462 us; speedup 1.0000x reference)
//
#include <hip/hip_runtime.h>

typedef _Float16 half_t;
typedef _Float16 h8 __attribute__((ext_vector_type(8)));
typedef _Float16 h4 __attribute__((ext_vector_type(4)));
typedef float f4 __attribute__((ext_vector_type(4)));

#define DEV __device__ __forceinline__

constexpr int Bc = 2, Sc = 4096, Ec = 1024, Hc = 16, Dc = 64, Wc = 256, Gc = 64;
constexpr float QSCALE = 0.125f;     // 1/sqrt(D)
constexpr float NEGV = -1e9f;

DEV f4 mfma16(h8 a, h8 b, f4 c) {
  return __builtin_amdgcn_mfma_f32_16x16x32_f16(a, b, c, 0, 0, 0);
}

DEV void gl_lds16(const half_t* g, half_t* l) {
  __builtin_amdgcn_global_load_lds((const __attribute__((address_space(1))) void*)g,
                                   (__attribute__((address_space(3))) void*)l, 16, 0, 0);
}

// ---------------- prep: x->f16  +  7 weight transposes, one dispatch ----------------
// blocks 0..8191: x cast (float4 each). blocks 8192..9983: weight transpose tiles.
__global__ void prep(const float* __restrict__ x,
                     const float* __restrict__ Wq, const float* __restrict__ Wk,
                     const float* __restrict__ Wv, const float* __restrict__ Wkg,
                     const float* __restrict__ Wvg, const float* __restrict__ Wqg,
                     const float* __restrict__ Wo,
                     half_t* __restrict__ xh, half_t* __restrict__ Wcat,
                     half_t* __restrict__ WtO) {
  __shared__ float tile[64][65];
  const int bx = blockIdx.x;
  if (bx < 8192) {
    int i = bx * 256 + threadIdx.x;
    float4 v = ((const float4*)x)[i];
    h4 o;
    o[0] = (half_t)v.x; o[1] = (half_t)v.y; o[2] = (half_t)v.z; o[3] = (half_t)v.w;
    ((h4*)xh)[i] = o;
    return;
  }
  const int widx = bx - 8192;
  const int y = widx >> 8;         // 0..6: q,k,v,kg,vg,qg,o
  const int xb = widx & 255;
  const float* W = (y == 0) ? Wq : (y == 1) ? Wk : (y == 2) ? Wv :
                   (y == 3) ? Wkg : (y == 4) ? Wvg : (y == 5) ? Wqg : Wo;
  half_t* Wt = (y < 6) ? (Wcat + (size_t)y * Ec * Ec) : WtO;
  const int bxt = xb & 15, byt = xb >> 4;
  const int tx = threadIdx.x & 63, ty = threadIdx.x >> 6;
  const int n0 = bxt * 64, k0 = byt * 64;
#pragma unroll
  for (int i = 0; i < 16; ++i) {
    int k = ty + i * 4;
    tile[k][tx] = W[(size_t)(k0 + k) * Ec + n0 + tx];
  }
  __syncthreads();
#pragma unroll
  for (int i = 0; i < 16; ++i) {
    int n = ty + i * 4;
    Wt[(size_t)(n0 + n) * Ec + k0 + tx] = (half_t)tile[tx][n];
  }
}

// ------ fused projection GEMM, BK=64: xh(8192x1024) @ Wcat(6144x1024)^T ------
// blockIdx.x<40: group g=col/1024: 0=q(BHSD,scale) 1=k(BHSD) 2=v(BHDS) 3=kg(BHSD) 4=vg(BHDS)
// blockIdx.x==40 (y<8): qg over 128 gathered rows (s<G per batch), g=5.
__global__ __launch_bounds__(256) void gemm_proj(const half_t* __restrict__ A,
                                                 const half_t* __restrict__ Bt,
                                                 const float* __restrict__ bq,
                                                 const float* __restrict__ bk,
                                                 const float* __restrict__ bv,
                                                 const float* __restrict__ bkg,
                                                 const float* __restrict__ bvg,
                                                 const float* __restrict__ bqg,
                                                 half_t* __restrict__ qh, half_t* __restrict__ kh,
                                                 half_t* __restrict__ vt, half_t* __restrict__ kgh,
                                                 half_t* __restrict__ vgt, half_t* __restrict__ qgh) {
  __shared__ __align__(16) half_t Ash[128 * 64];
  __shared__ __align__(16) half_t Bsh[128 * 64];
  const bool qgblk = (blockIdx.x == 40);
  if (qgblk && blockIdx.y >= 8) return;
  const int tid = threadIdx.x;
  const int wv = tid >> 6, lane = tid & 63;
  const int mr = lane & 15, qd = lane >> 4;
  const int wv_m = wv >> 1, wv_n = wv & 1;
  const int col0 = qgblk ? (5 * Ec + (int)blockIdx.y * 128) : (int)blockIdx.x * 128;
  const int row0 = qgblk ? 0 : (int)blockIdx.y * 128;
  const int g = col0 >> 10;

  f4 acc[4][4] = {};

  for (int k0 = 0; k0 < Ec; k0 += 64) {
#pragma unroll
    for (int i = 0; i < 4; ++i) {
      int slot = wv * 256 + i * 64 + lane;
      int r = slot >> 3;
      int kc = (slot & 7) ^ (r & 7);  // row-spread swizzle (measured conflict-free)
      int ar = qgblk ? ((r < 64) ? r : 4032 + r) : (row0 + r);
      gl_lds16(A + (size_t)ar * Ec + k0 + kc * 8, Ash + (size_t)(wv * 256 + i * 64) * 8);
      gl_lds16(Bt + (size_t)(col0 + r) * Ec + k0 + kc * 8, Bsh + (size_t)(wv * 256 + i * 64) * 8);
    }
    __syncthreads();
#pragma unroll
    for (int u = 0; u < 2; ++u) {
      h8 af[4], bf[4];
#pragma unroll
      for (int mt = 0; mt < 4; ++mt) {
        int r = wv_m * 64 + mt * 16 + mr;
        af[mt] = *(const h8*)(Ash + (size_t)(r * 8 + ((qd + u * 4) ^ (r & 7))) * 8);
      }
#pragma unroll
      for (int nt = 0; nt < 4; ++nt) {
        int r = wv_n * 64 + nt * 16 + mr;
        bf[nt] = *(const h8*)(Bsh + (size_t)(r * 8 + ((qd + u * 4) ^ (r & 7))) * 8);
      }
#pragma unroll
      for (int mt = 0; mt < 4; ++mt)
#pragma unroll
        for (int nt = 0; nt < 4; ++nt)
          acc[mt][nt] = mfma16(af[mt], bf[nt], acc[mt][nt]);
    }
    __syncthreads();
  }

  const float* bptr = (g == 0) ? bq : (g == 1) ? bk : (g == 2) ? bv :
                      (g == 3) ? bkg : (g == 4) ? bvg : bqg;
#pragma unroll
  for (int mt = 0; mt < 4; ++mt) {
#pragma unroll
    for (int nt = 0; nt < 4; ++nt) {
      const int C = col0 + wv_n * 64 + nt * 16 + mr;
      const int c1 = C & 1023, hh = c1 >> 6, d = c1 & 63;
      const float bval = bptr[c1];
      const int Rbase = row0 + wv_m * 64 + mt * 16 + qd * 4;
      f4 a = acc[mt][nt];
      if (g == 2 || g == 4) {  // transposed (B,H,D,S)
        half_t* O = (g == 2) ? vt : vgt;
        int b = Rbase >> 12, s = Rbase & 4095;
        h4 pk;
#pragma unroll
        for (int r = 0; r < 4; ++r) pk[r] = (half_t)(a[r] + bval);
        *(h4*)(O + ((size_t)(b * Hc + hh) * Dc + d) * Sc + s) = pk;
      } else if (g == 5) {     // qg: (B,H,G,D), gathered rows
#pragma unroll
        for (int r = 0; r < 4; ++r) {
          int rr = Rbase + r;
          int b = rr >> 6, s = rr & 63;
          qgh[((size_t)(b * Hc + hh) * Gc + s) * Dc + d] = (half_t)((a[r] + bval) * QSCALE);
        }
      } else {                 // (B,H,S,D), q scaled
        half_t* O = (g == 0) ? qh : (g == 1) ? kh : kgh;
        const float scale = (g == 0) ? QSCALE : 1.0f;
#pragma unroll
        for (int r = 0; r < 4; ++r) {
          int R = Rbase + r;
          int b = R >> 12, s = R & 4095;
          O[((size_t)(b * Hc + hh) * Sc + s) * Dc + d] = (half_t)((a[r] + bval) * scale);
        }
      }
    }
  }
}

// ---------------- output GEMM, BK=64: ctx(8192x1024) @ WtO^T + bo -> fp32 ----------------
__global__ __launch_bounds__(256) void gemm_out(const half_t* __restrict__ A,
                                                const half_t* __restrict__ Bt,
                                                const float* __restrict__ bias,
                                                float* __restrict__ O) {
  __shared__ __align__(16) half_t Ash[128 * 64];
  __shared__ __align__(16) half_t Bsh[128 * 64];
  const int tid = threadIdx.x;
  const int wv = tid >> 6, lane = tid & 63;
  const int mr = lane & 15, qd = lane >> 4;
  const int wv_m = wv >> 1, wv_n = wv & 1;
  const int col0 = blockIdx.x * 128;
  const int row0 = blockIdx.y * 128;

  f4 acc[4][4] = {};

  for (int k0 = 0; k0 < Ec; k0 += 64) {
#pragma unroll
    for (int i = 0; i < 4; ++i) {
      int slot = wv * 256 + i * 64 + lane;
      int r = slot >> 3;
      int kc = (slot & 7) ^ (r & 7);
      gl_lds16(A + (size_t)(row0 + r) * Ec + k0 + kc * 8, Ash + (size_t)(wv * 256 + i * 64) * 8);
      gl_lds16(Bt + (size_t)(col0 + r) * Ec + k0 + kc * 8, Bsh + (size_t)(wv * 256 + i * 64) * 8);
    }
    __syncthreads();
#pragma unroll
    for (int u = 0; u < 2; ++u) {
      h8 af[4], bf[4];
#pragma unroll
      for (int mt = 0; mt < 4; ++mt) {
        int r = wv_m * 64 + mt * 16 + mr;
        af[mt] = *(const h8*)(Ash + (size_t)(r * 8 + ((qd + u * 4) ^ (r & 7))) * 8);
      }
#pragma unroll
      for (int nt = 0; nt < 4; ++nt) {
        int r = wv_n * 64 + nt * 16 + mr;
        bf[nt] = *(const h8*)(Bsh + (size_t)(r * 8 + ((qd + u * 4) ^ (r & 7))) * 8);
      }
#pragma unroll
      for (int mt = 0; mt < 4; ++mt)
#pragma unroll
        for (int nt = 0; nt < 4; ++nt)
          acc[mt][nt] = mfma16(af[mt], bf[nt], acc[mt][nt]);
    }
    __syncthreads();
  }

#pragma unroll
  for (int mt = 0; mt < 4; ++mt) {
#pragma unroll
    for (int nt = 0; nt < 4; ++nt) {
      const int C = col0 + wv_n * 64 + nt * 16 + mr;
      const float bval = bias[C];
      const int Rbase = row0 + wv_m * 64 + mt * 16 + qd * 4;
      f4 a = acc[mt][nt];
#pragma unroll
      for (int r = 0; r < 4; ++r)
        O[(size_t)(Rbase + r) * Ec + C] = a[r] + bval;
    }
  }
}

// ---------------- windowed + global-key attention (flash-style, LDS-staged) ----------------
__global__ __launch_bounds__(256) void win_attn(const half_t* __restrict__ qh,
                                                const half_t* __restrict__ kh,
                                                const half_t* __restrict__ vt,
                                                half_t* __restrict__ ctx) {
  constexpr int PST = 88;
  __shared__ __align__(16) half_t Kb[2][64 * 64];
  __shared__ __align__(16) half_t Vb[2][64 * 64];
  __shared__ __align__(16) half_t Pl[4][16 * PST];
  const int bid = blockIdx.x;
  const int qc = bid & 15, h = (bid >> 4) & 15, b = bid >> 8;
  const int qs = qc << 8;
  const int tid = threadIdx.x, wv = tid >> 6, lane = tid & 63;
  const int mr = lane & 15, qd = lane >> 4;
  const int qw = qs + wv * 64;
  const size_t bh = (size_t)(b * Hc + h);
  const half_t* qb = qh + bh * Sc * Dc;
  const half_t* kb = kh + bh * Sc * Dc;
  const half_t* vb = vt + bh * Dc * Sc;
  half_t* Pw = &Pl[wv][0];

  h8 qf[4][2];
#pragma unroll
  for (int qt = 0; qt < 4; ++qt) {
    const half_t* qrow = qb + (size_t)(qw + qt * 16 + mr) * Dc;
    qf[qt][0] = *(const h8*)(qrow + qd * 8);
    qf[qt][1] = *(const h8*)(qrow + 32 + qd * 8);
  }

  int tiles[14];
  int nT = 0;
  tiles[nT++] = 0;
  {
    int lo = qs - Wc; if (lo < Gc) lo = Gc;
    int hi = qs + 448; if (hi > Sc - 64) hi = Sc - 64;
    for (int kp0 = lo; kp0 <= hi; kp0 += 64) tiles[nT++] = kp0;
  }

  auto stage = [&](int kp0, int bi) {
#pragma unroll
    for (int i = 0; i < 2; ++i) {
      const int seg = wv * 2 + i;
      const int s = seg * 64 + lane;
      const int r = s >> 3;
      const int kc = (s & 7) ^ (r & 7);
      gl_lds16(kb + (size_t)(kp0 + r) * Dc + kc * 8, &Kb[bi][seg * 512]);
      gl_lds16(vb + (size_t)r * Sc + kp0 + kc * 8, &Vb[bi][seg * 512]);
    }
  };

  float m_run[4], l_run[4];
  f4 acc[4][4] = {};
#pragma unroll
  for (int qt = 0; qt < 4; ++qt) { m_run[qt] = -1e30f; l_run[qt] = 0.f; }

  stage(tiles[0], 0);

  for (int t = 0; t < nT; ++t) {
    __syncthreads();
    if (t + 1 < nT) stage(tiles[t + 1], (t + 1) & 1);
    const int kp0 = tiles[t];
    if (t > 0 && (kp0 > qw + 319 || kp0 + 63 < qw - Wc)) continue;

    const half_t* BK = Kb[t & 1];
    const half_t* BV = Vb[t & 1];
    h8 kf[4][2], vf[4][2];
#pragma unroll
    for (int mt = 0; mt < 4; ++mt) {
      const int row = mt * 16 + mr, r7 = row & 7;
      kf[mt][0] = *(const h8*)(BK + (size_t)(row * 8 + (qd ^ r7)) * 8);
      kf[mt][1] = *(const h8*)(BK + (size_t)(row * 8 + ((qd + 4) ^ r7)) * 8);
      vf[mt][0] = *(const h8*)(BV + (size_t)(row * 8 + (qd ^ r7)) * 8);
      vf[mt][1] = *(const h8*)(BV + (size_t)(row * 8 + ((qd + 4) ^ r7)) * 8);
    }
    const bool nomask = (t == 0) || (kp0 >= qw - 193 && kp0 <= qw + 193);

#pragma unroll
    for (int qt = 0; qt < 4; ++qt) {
      f4 sa[4];
#pragma unroll
      for (int mt = 0; mt < 4; ++mt) {
        f4 s = {};
        s = mfma16(kf[mt][0], qf[qt][0], s);
        s = mfma16(kf[mt][1], qf[qt][1], s);
        sa[mt] = s;
      }
      const int q = qw + qt * 16 + mr;
      if (!nomask) {
#pragma unroll
        for (int mt = 0; mt < 4; ++mt)
#pragma unroll
          for (int r = 0; r < 4; ++r) {
            const int kp = kp0 + mt * 16 + qd * 4 + r;
            if (kp < q - Wc || kp > q + Wc) sa[mt][r] = NEGV;
          }
      }
      float tm = -1e30f;
#pragma unroll
      for (int mt = 0; mt < 4; ++mt)
#pragma unroll
        for (int r = 0; r < 4; ++r) tm = fmaxf(tm, sa[mt][r]);
      tm = fmaxf(tm, __shfl_xor(tm, 16));
      tm = fmaxf(tm, __shfl_xor(tm, 32));
      const float mnew = fmaxf(m_run[qt], tm);
      const float alpha = __expf(m_run[qt] - mnew);
      m_run[qt] = mnew;
      float psum = 0.0f;
#pragma unroll
      for (int mt = 0; mt < 4; ++mt) {
        h4 pk;
#pragma unroll
        for (int r = 0; r < 4; ++r) {
          const float p = __expf(sa[mt][r] - mnew);
          psum += p;
          pk[r] = (half_t)p;
        }
        *(h4*)(Pw + mr * PST + mt * 16 + qd * 4) = pk;
      }
      psum += __shfl_xor(psum, 16);
      psum += __shfl_xor(psum, 32);
      l_run[qt] = l_run[qt] * alpha + psum;
#pragma unroll
      for (int mt = 0; mt < 4; ++mt)
#pragma unroll
        for (int r = 0; r < 4; ++r) acc[qt][mt][r] *= alpha;
      const h8 p0 = *(const h8*)(Pw + mr * PST + qd * 8);
      const h8 p1 = *(const h8*)(Pw + mr * PST + 32 + qd * 8);
#pragma unroll
      for (int mt = 0; mt < 4; ++mt) {
        acc[qt][mt] = mfma16(vf[mt][0], p0, acc[qt][mt]);
        acc[qt][mt] = mfma16(vf[mt][1], p1, acc[qt][mt]);
      }
    }
  }

#pragma unroll
  for (int qt = 0; qt < 4; ++qt) {
    const float inv = 1.0f / l_run[qt];
    const int q = qw + qt * 16 + mr;
    half_t* crow = ctx + ((size_t)(b * Sc) + q) * Ec + h * Dc;
#pragma unroll
    for (int mt = 0; mt < 4; ++mt) {
      h4 pk;
#pragma unroll
      for (int r = 0; r < 4; ++r) pk[r] = (half_t)(acc[qt][mt][r] * inv);
      *(h4*)(crow + mt * 16 + qd * 4) = pk;
    }
  }
}

// ---------------- global-query attention, fused flash-style (one kernel) ----------------
// block = (b,h); wave wv owns 16 queries; iterate 64 key-tiles over full S.
__global__ __launch_bounds__(256) void gq_fused(const half_t* __restrict__ qgh,
                                                const half_t* __restrict__ kgh,
                                                const half_t* __restrict__ vgt,
                                                half_t* __restrict__ ctx) {
  constexpr int PST = 88;
  __shared__ __align__(16) half_t Pl[4][16 * PST];
  const int h = blockIdx.x & 15, b = blockIdx.x >> 4;
  const int tid = threadIdx.x, wv = tid >> 6, lane = tid & 63;
  const int mr = lane & 15, qd = lane >> 4;
  const size_t bh = (size_t)(b * Hc + h);
  const half_t* qb = qgh + bh * Gc * Dc;
  const half_t* kb = kgh + bh * Sc * Dc;
  const half_t* vb = vgt + bh * Dc * Sc;
  half_t* Pw = &Pl[wv][0];

  const int qrow = wv * 16 + mr;
  const h8 qf0 = *(const h8*)(qb + (size_t)qrow * Dc + qd * 8);
  const h8 qf1 = *(const h8*)(qb + (size_t)qrow * Dc + 32 + qd * 8);

  float m_run = -1e30f, l_run = 0.f;
  f4 acc[4] = {};

  for (int t = 0; t < 64; ++t) {
    const int kp0 = t * 64;
    f4 sa[4];
#pragma unroll
    for (int mt = 0; mt < 4; ++mt) {
      const int kp = kp0 + mt * 16 + mr;
      h8 kf0 = *(const h8*)(kb + (size_t)kp * Dc + qd * 8);
      h8 kf1 = *(const h8*)(kb + (size_t)kp * Dc + 32 + qd * 8);
      f4 s = {};
      s = mfma16(kf0, qf0, s);
      s = mfma16(kf1, qf1, s);
      sa[mt] = s;
    }
    float tm = -1e30f;
#pragma unroll
    for (int mt = 0; mt < 4; ++mt)
#pragma unroll
      for (int r = 0; r < 4; ++r) tm = fmaxf(tm, sa[mt][r]);
    tm = fmaxf(tm, __shfl_xor(tm, 16));
    tm = fmaxf(tm, __shfl_xor(tm, 32));
    const float mnew = fmaxf(m_run, tm);
    const float alpha = __expf(m_run - mnew);
    m_run = mnew;
    float psum = 0.0f;
#pragma unroll
    for (int mt = 0; mt < 4; ++mt) {
      h4 pk;
#pragma unroll
      for (int r = 0; r < 4; ++r) {
        const float p = __expf(sa[mt][r] - mnew);
        psum += p;
        pk[r] = (half_t)p;
      }
      *(h4*)(Pw + mr * PST + mt * 16 + qd * 4) = pk;
    }
    psum += __shfl_xor(psum, 16);
    psum += __shfl_xor(psum, 32);
    l_run = l_run * alpha + psum;
#pragma unroll
    for (int mt = 0; mt < 4; ++mt)
#pragma unroll
      for (int r = 0; r < 4; ++r) acc[mt][r] *= alpha;
    const h8 p0 = *(const h8*)(Pw + mr * PST + qd * 8);
    const h8 p1 = *(const h8*)(Pw + mr * PST + 32 + qd * 8);
#pragma unroll
    for (int mt = 0; mt < 4; ++mt) {
      const h8 vf0 = *(const h8*)(vb + (size_t)(mt * 16 + mr) * Sc + kp0 + qd * 8);
      const h8 vf1 = *(const h8*)(vb + (size_t)(mt * 16 + mr) * Sc + kp0 + 32 + qd * 8);
      acc[mt] = mfma16(vf0, p0, acc[mt]);
      acc[mt] = mfma16(vf1, p1, acc[mt]);
    }
  }

  const float inv = 1.0f / l_run;
  const int g = wv * 16 + mr;
  half_t* crow = ctx + ((size_t)(b * Sc) + g) * Ec + h * Dc;
#pragma unroll
  for (int mt = 0; mt < 4; ++mt) {
    h4 pk;
#pragma unroll
    for (int r = 0; r < 4; ++r) pk[r] = (half_t)(acc[mt][r] * inv);
    *(h4*)(crow + mt * 16 + qd * 4) = pk;
  }
}

// ---------------- host launch ----------------

extern "C" void kernel_launch(void* const* d_in, const int* in_sizes, int n_in,
                              void* d_out, int out_size, void* d_ws, size_t ws_size,
                              hipStream_t stream) {
  const float* x   = (const float*)d_in[0];
  const float* Wq  = (const float*)d_in[2];
  const float* bq  = (const float*)d_in[3];
  const float* Wk  = (const float*)d_in[4];
  const float* bk  = (const float*)d_in[5];
  const float* Wv  = (const float*)d_in[6];
  const float* bv  = (const float*)d_in[7];
  const float* Wqg = (const float*)d_in[8];
  const float* bqg = (const float*)d_in[9];
  const float* Wkg = (const float*)d_in[10];
  const float* bkg = (const float*)d_in[11];
  const float* Wvg = (const float*)d_in[12];
  const float* bvg = (const float*)d_in[13];
  const float* Wo  = (const float*)d_in[14];
  const float* bo  = (const float*)d_in[15];
  float* out = (float*)d_out;

  char* ws = (char*)d_ws;
  size_t off = 0;
  auto alloc = [&](size_t bytes) {
    void* p = ws + off;
    off = (off + bytes + 255) & ~(size_t)255;
    return p;
  };
  const size_t BSE2 = (size_t)Bc * Sc * Ec * 2;
  const size_t W2 = (size_t)Ec * Ec * 2;
  half_t* xh   = (half_t*)alloc(BSE2);
  half_t* Wcat = (half_t*)alloc(W2 * 6);   // q,k,v,kg,vg,qg transposed f16
  half_t* WtO  = (half_t*)alloc(W2);
  half_t* qh   = (half_t*)alloc(BSE2);     // (B,H,S,D) scaled
  half_t* kh   = (half_t*)alloc(BSE2);     // (B,H,S,D)
  half_t* vt   = (half_t*)alloc(BSE2);     // (B,H,D,S)
  half_t* kgh  = (half_t*)alloc(BSE2);     // (B,H,S,D)
  half_t* vgt  = (half_t*)alloc(BSE2);     // (B,H,D,S)
  half_t* qgh  = (half_t*)alloc((size_t)Bc * Hc * Gc * Dc * 2);
  half_t* ctx  = (half_t*)alloc(BSE2);
  (void)ws_size; (void)in_sizes; (void)n_in; (void)out_size;

  prep<<<8192 + 7 * 256, 256, 0, stream>>>(x, Wq, Wk, Wv, Wkg, Wvg, Wqg, Wo,
                                           xh, Wcat, WtO);

  gemm_proj<<<dim3(41, 64), 256, 0, stream>>>(xh, Wcat, bq, bk, bv, bkg, bvg, bqg,
                                              qh, kh, vt, kgh, vgt, qgh);

  win_attn<<<Bc * Hc * (Sc / 256), 256, 0, stream>>>(qh, kh, vt, ctx);

  gq_fused<<<Bc * Hc, 256, 0, stream>>>(qgh, kgh, vgt, ctx);

  gemm_out<<<dim3(8, 64), 256, 0, stream>>>(ctx, WtO, bo, out);
}

// Round 6
// 495.377 us; speedup vs baseline: 1.0204x; 1.0204x over previous
//
#include <hip/hip_runtime.h>

typedef _Float16 half_t;
typedef _Float16 h8 __attribute__((ext_vector_type(8)));
typedef _Float16 h4 __attribute__((ext_vector_type(4)));
typedef float f4 __attribute__((ext_vector_type(4)));

#define DEV __device__ __forceinline__

constexpr int Bc = 2, Sc = 4096, Ec = 1024, Hc = 16, Dc = 64, Wc = 256, Gc = 64;
constexpr float QSCALE = 0.125f;     // 1/sqrt(D)
constexpr float NEGV = -1e9f;

DEV f4 mfma16(h8 a, h8 b, f4 c) {
  return __builtin_amdgcn_mfma_f32_16x16x32_f16(a, b, c, 0, 0, 0);
}

DEV void gl_lds16(const half_t* g, half_t* l) {
  __builtin_amdgcn_global_load_lds((const __attribute__((address_space(1))) void*)g,
                                   (__attribute__((address_space(3))) void*)l, 16, 0, 0);
}

// ---------------- prep: x->f16  +  7 weight transposes, one dispatch ----------------
__global__ void prep(const float* __restrict__ x,
                     const float* __restrict__ Wq, const float* __restrict__ Wk,
                     const float* __restrict__ Wv, const float* __restrict__ Wkg,
                     const float* __restrict__ Wvg, const float* __restrict__ Wqg,
                     const float* __restrict__ Wo,
                     half_t* __restrict__ xh, half_t* __restrict__ Wcat,
                     half_t* __restrict__ WtO) {
  __shared__ float tile[64][65];
  const int bx = blockIdx.x;
  if (bx < 8192) {
    int i = bx * 256 + threadIdx.x;
    float4 v = ((const float4*)x)[i];
    h4 o;
    o[0] = (half_t)v.x; o[1] = (half_t)v.y; o[2] = (half_t)v.z; o[3] = (half_t)v.w;
    ((h4*)xh)[i] = o;
    return;
  }
  const int widx = bx - 8192;
  const int y = widx >> 8;         // 0..6: q,k,v,kg,vg,qg,o
  const int xb = widx & 255;
  const float* W = (y == 0) ? Wq : (y == 1) ? Wk : (y == 2) ? Wv :
                   (y == 3) ? Wkg : (y == 4) ? Wvg : (y == 5) ? Wqg : Wo;
  half_t* Wt = (y < 6) ? (Wcat + (size_t)y * Ec * Ec) : WtO;
  const int bxt = xb & 15, byt = xb >> 4;
  const int tx = threadIdx.x & 63, ty = threadIdx.x >> 6;
  const int n0 = bxt * 64, k0 = byt * 64;
#pragma unroll
  for (int i = 0; i < 16; ++i) {
    int k = ty + i * 4;
    tile[k][tx] = W[(size_t)(k0 + k) * Ec + n0 + tx];
  }
  __syncthreads();
#pragma unroll
  for (int i = 0; i < 16; ++i) {
    int n = ty + i * 4;
    Wt[(size_t)(n0 + n) * Ec + k0 + tx] = (half_t)tile[tx][n];
  }
}

// ------ fused projection GEMM, BK=32: xh(8192x1024) @ Wcat(6144x1024)^T ------
// blockIdx.x<40: g=col/1024: 0=q(BHSD,scale) 1=k(BHSD) 2=v(BHDS) 3=kg(BHSD) 4=vg(BHDS)
// blockIdx.x==40 (y<8): qg over 128 gathered rows (s<G per batch), g=5.
// BK=32 / 16KB LDS: 4+ blocks/CU (BK=64 regressed — m132-style occupancy cliff, R5).
__global__ __launch_bounds__(256) void gemm_proj(const half_t* __restrict__ A,
                                                 const half_t* __restrict__ Bt,
                                                 const float* __restrict__ bq,
                                                 const float* __restrict__ bk,
                                                 const float* __restrict__ bv,
                                                 const float* __restrict__ bkg,
                                                 const float* __restrict__ bvg,
                                                 const float* __restrict__ bqg,
                                                 half_t* __restrict__ qh, half_t* __restrict__ kh,
                                                 half_t* __restrict__ vt, half_t* __restrict__ kgh,
                                                 half_t* __restrict__ vgt, half_t* __restrict__ qgh) {
  __shared__ __align__(16) half_t Ash[128 * 32];
  __shared__ __align__(16) half_t Bsh[128 * 32];
  const bool qgblk = (blockIdx.x == 40);
  if (qgblk && blockIdx.y >= 8) return;
  const int tid = threadIdx.x;
  const int wv = tid >> 6, lane = tid & 63;
  const int mr = lane & 15, qd = lane >> 4;
  const int wv_m = wv >> 1, wv_n = wv & 1;
  const int col0 = qgblk ? (5 * Ec + (int)blockIdx.y * 128) : (int)blockIdx.x * 128;
  const int row0 = qgblk ? 0 : (int)blockIdx.y * 128;
  const int g = col0 >> 10;

  f4 acc[4][4] = {};

  for (int k0 = 0; k0 < Ec; k0 += 32) {
#pragma unroll
    for (int i = 0; i < 2; ++i) {
      int slot = wv * 128 + i * 64 + lane;
      int r = slot >> 2;
      int kc = (slot & 3) ^ ((r >> 1) & 3);  // parity-spread swizzle (0 conflicts, R4)
      int ar = qgblk ? ((r < 64) ? r : 4032 + r) : (row0 + r);
      gl_lds16(A + (size_t)ar * Ec + k0 + kc * 8, Ash + (size_t)(wv * 128 + i * 64) * 8);
      gl_lds16(Bt + (size_t)(col0 + r) * Ec + k0 + kc * 8, Bsh + (size_t)(wv * 128 + i * 64) * 8);
    }
    __syncthreads();
    h8 af[4], bf[4];
#pragma unroll
    for (int mt = 0; mt < 4; ++mt) {
      int r = wv_m * 64 + mt * 16 + mr;
      af[mt] = *(const h8*)(Ash + (size_t)((r << 2) | (qd ^ ((r >> 1) & 3))) * 8);
    }
#pragma unroll
    for (int nt = 0; nt < 4; ++nt) {
      int r = wv_n * 64 + nt * 16 + mr;
      bf[nt] = *(const h8*)(Bsh + (size_t)((r << 2) | (qd ^ ((r >> 1) & 3))) * 8);
    }
#pragma unroll
    for (int mt = 0; mt < 4; ++mt)
#pragma unroll
      for (int nt = 0; nt < 4; ++nt)
        acc[mt][nt] = mfma16(af[mt], bf[nt], acc[mt][nt]);
    __syncthreads();
  }

  const float* bptr = (g == 0) ? bq : (g == 1) ? bk : (g == 2) ? bv :
                      (g == 3) ? bkg : (g == 4) ? bvg : bqg;
#pragma unroll
  for (int mt = 0; mt < 4; ++mt) {
#pragma unroll
    for (int nt = 0; nt < 4; ++nt) {
      const int C = col0 + wv_n * 64 + nt * 16 + mr;
      const int c1 = C & 1023, hh = c1 >> 6, d = c1 & 63;
      const float bval = bptr[c1];
      const int Rbase = row0 + wv_m * 64 + mt * 16 + qd * 4;
      f4 a = acc[mt][nt];
      if (g == 2 || g == 4) {  // transposed (B,H,D,S)
        half_t* O = (g == 2) ? vt : vgt;
        int b = Rbase >> 12, s = Rbase & 4095;
        h4 pk;
#pragma unroll
        for (int r = 0; r < 4; ++r) pk[r] = (half_t)(a[r] + bval);
        *(h4*)(O + ((size_t)(b * Hc + hh) * Dc + d) * Sc + s) = pk;
      } else if (g == 5) {     // qg: (B,H,G,D), gathered rows
#pragma unroll
        for (int r = 0; r < 4; ++r) {
          int rr = Rbase + r;
          int b = rr >> 6, s = rr & 63;
          qgh[((size_t)(b * Hc + hh) * Gc + s) * Dc + d] = (half_t)((a[r] + bval) * QSCALE);
        }
      } else {                 // (B,H,S,D), q scaled
        half_t* O = (g == 0) ? qh : (g == 1) ? kh : kgh;
        const float scale = (g == 0) ? QSCALE : 1.0f;
#pragma unroll
        for (int r = 0; r < 4; ++r) {
          int R = Rbase + r;
          int b = R >> 12, s = R & 4095;
          O[((size_t)(b * Hc + hh) * Sc + s) * Dc + d] = (half_t)((a[r] + bval) * scale);
        }
      }
    }
  }
}

// ---------------- output GEMM, BK=32: ctx(8192x1024) @ WtO^T + bo -> fp32 ----------------
__global__ __launch_bounds__(256) void gemm_out(const half_t* __restrict__ A,
                                                const half_t* __restrict__ Bt,
                                                const float* __restrict__ bias,
                                                float* __restrict__ O) {
  __shared__ __align__(16) half_t Ash[128 * 32];
  __shared__ __align__(16) half_t Bsh[128 * 32];
  const int tid = threadIdx.x;
  const int wv = tid >> 6, lane = tid & 63;
  const int mr = lane & 15, qd = lane >> 4;
  const int wv_m = wv >> 1, wv_n = wv & 1;
  const int col0 = blockIdx.x * 128;
  const int row0 = blockIdx.y * 128;

  f4 acc[4][4] = {};

  for (int k0 = 0; k0 < Ec; k0 += 32) {
#pragma unroll
    for (int i = 0; i < 2; ++i) {
      int slot = wv * 128 + i * 64 + lane;
      int r = slot >> 2;
      int kc = (slot & 3) ^ ((r >> 1) & 3);
      gl_lds16(A + (size_t)(row0 + r) * Ec + k0 + kc * 8, Ash + (size_t)(wv * 128 + i * 64) * 8);
      gl_lds16(Bt + (size_t)(col0 + r) * Ec + k0 + kc * 8, Bsh + (size_t)(wv * 128 + i * 64) * 8);
    }
    __syncthreads();
    h8 af[4], bf[4];
#pragma unroll
    for (int mt = 0; mt < 4; ++mt) {
      int r = wv_m * 64 + mt * 16 + mr;
      af[mt] = *(const h8*)(Ash + (size_t)((r << 2) | (qd ^ ((r >> 1) & 3))) * 8);
    }
#pragma unroll
    for (int nt = 0; nt < 4; ++nt) {
      int r = wv_n * 64 + nt * 16 + mr;
      bf[nt] = *(const h8*)(Bsh + (size_t)((r << 2) | (qd ^ ((r >> 1) & 3))) * 8);
    }
#pragma unroll
    for (int mt = 0; mt < 4; ++mt)
#pragma unroll
      for (int nt = 0; nt < 4; ++nt)
        acc[mt][nt] = mfma16(af[mt], bf[nt], acc[mt][nt]);
    __syncthreads();
  }

#pragma unroll
  for (int mt = 0; mt < 4; ++mt) {
#pragma unroll
    for (int nt = 0; nt < 4; ++nt) {
      const int C = col0 + wv_n * 64 + nt * 16 + mr;
      const float bval = bias[C];
      const int Rbase = row0 + wv_m * 64 + mt * 16 + qd * 4;
      f4 a = acc[mt][nt];
#pragma unroll
      for (int r = 0; r < 4; ++r)
        O[(size_t)(Rbase + r) * Ec + C] = a[r] + bval;
    }
  }
}

// ---------------- windowed + global-key attention (flash-style, LDS-staged) ----------------
__global__ __launch_bounds__(256) void win_attn(const half_t* __restrict__ qh,
                                                const half_t* __restrict__ kh,
                                                const half_t* __restrict__ vt,
                                                half_t* __restrict__ ctx) {
  constexpr int PST = 88;
  __shared__ __align__(16) half_t Kb[2][64 * 64];
  __shared__ __align__(16) half_t Vb[2][64 * 64];
  __shared__ __align__(16) half_t Pl[4][16 * PST];
  const int bid = blockIdx.x;
  const int qc = bid & 15, h = (bid >> 4) & 15, b = bid >> 8;
  const int qs = qc << 8;
  const int tid = threadIdx.x, wv = tid >> 6, lane = tid & 63;
  const int mr = lane & 15, qd = lane >> 4;
  const int qw = qs + wv * 64;
  const size_t bh = (size_t)(b * Hc + h);
  const half_t* qb = qh + bh * Sc * Dc;
  const half_t* kb = kh + bh * Sc * Dc;
  const half_t* vb = vt + bh * Dc * Sc;
  half_t* Pw = &Pl[wv][0];

  h8 qf[4][2];
#pragma unroll
  for (int qt = 0; qt < 4; ++qt) {
    const half_t* qrow = qb + (size_t)(qw + qt * 16 + mr) * Dc;
    qf[qt][0] = *(const h8*)(qrow + qd * 8);
    qf[qt][1] = *(const h8*)(qrow + 32 + qd * 8);
  }

  int tiles[14];
  int nT = 0;
  tiles[nT++] = 0;
  {
    int lo = qs - Wc; if (lo < Gc) lo = Gc;
    int hi = qs + 448; if (hi > Sc - 64) hi = Sc - 64;
    for (int kp0 = lo; kp0 <= hi; kp0 += 64) tiles[nT++] = kp0;
  }

  auto stage = [&](int kp0, int bi) {
#pragma unroll
    for (int i = 0; i < 2; ++i) {
      const int seg = wv * 2 + i;
      const int s = seg * 64 + lane;
      const int r = s >> 3;
      const int kc = (s & 7) ^ (r & 7);
      gl_lds16(kb + (size_t)(kp0 + r) * Dc + kc * 8, &Kb[bi][seg * 512]);
      gl_lds16(vb + (size_t)r * Sc + kp0 + kc * 8, &Vb[bi][seg * 512]);
    }
  };

  float m_run[4], l_run[4];
  f4 acc[4][4] = {};
#pragma unroll
  for (int qt = 0; qt < 4; ++qt) { m_run[qt] = -1e30f; l_run[qt] = 0.f; }

  stage(tiles[0], 0);

  for (int t = 0; t < nT; ++t) {
    __syncthreads();
    if (t + 1 < nT) stage(tiles[t + 1], (t + 1) & 1);
    const int kp0 = tiles[t];
    if (t > 0 && (kp0 > qw + 319 || kp0 + 63 < qw - Wc)) continue;

    const half_t* BK = Kb[t & 1];
    const half_t* BV = Vb[t & 1];
    h8 kf[4][2], vf[4][2];
#pragma unroll
    for (int mt = 0; mt < 4; ++mt) {
      const int row = mt * 16 + mr, r7 = row & 7;
      kf[mt][0] = *(const h8*)(BK + (size_t)(row * 8 + (qd ^ r7)) * 8);
      kf[mt][1] = *(const h8*)(BK + (size_t)(row * 8 + ((qd + 4) ^ r7)) * 8);
      vf[mt][0] = *(const h8*)(BV + (size_t)(row * 8 + (qd ^ r7)) * 8);
      vf[mt][1] = *(const h8*)(BV + (size_t)(row * 8 + ((qd + 4) ^ r7)) * 8);
    }
    const bool nomask = (t == 0) || (kp0 >= qw - 193 && kp0 <= qw + 193);

#pragma unroll
    for (int qt = 0; qt < 4; ++qt) {
      f4 sa[4];
#pragma unroll
      for (int mt = 0; mt < 4; ++mt) {
        f4 s = {};
        s = mfma16(kf[mt][0], qf[qt][0], s);
        s = mfma16(kf[mt][1], qf[qt][1], s);
        sa[mt] = s;
      }
      const int q = qw + qt * 16 + mr;
      if (!nomask) {
#pragma unroll
        for (int mt = 0; mt < 4; ++mt)
#pragma unroll
          for (int r = 0; r < 4; ++r) {
            const int kp = kp0 + mt * 16 + qd * 4 + r;
            if (kp < q - Wc || kp > q + Wc) sa[mt][r] = NEGV;
          }
      }
      float tm = -1e30f;
#pragma unroll
      for (int mt = 0; mt < 4; ++mt)
#pragma unroll
        for (int r = 0; r < 4; ++r) tm = fmaxf(tm, sa[mt][r]);
      tm = fmaxf(tm, __shfl_xor(tm, 16));
      tm = fmaxf(tm, __shfl_xor(tm, 32));
      const float mnew = fmaxf(m_run[qt], tm);
      const float alpha = __expf(m_run[qt] - mnew);
      m_run[qt] = mnew;
      float psum = 0.0f;
#pragma unroll
      for (int mt = 0; mt < 4; ++mt) {
        h4 pk;
#pragma unroll
        for (int r = 0; r < 4; ++r) {
          const float p = __expf(sa[mt][r] - mnew);
          psum += p;
          pk[r] = (half_t)p;
        }
        *(h4*)(Pw + mr * PST + mt * 16 + qd * 4) = pk;
      }
      psum += __shfl_xor(psum, 16);
      psum += __shfl_xor(psum, 32);
      l_run[qt] = l_run[qt] * alpha + psum;
#pragma unroll
      for (int mt = 0; mt < 4; ++mt)
#pragma unroll
        for (int r = 0; r < 4; ++r) acc[qt][mt][r] *= alpha;
      const h8 p0 = *(const h8*)(Pw + mr * PST + qd * 8);
      const h8 p1 = *(const h8*)(Pw + mr * PST + 32 + qd * 8);
#pragma unroll
      for (int mt = 0; mt < 4; ++mt) {
        acc[qt][mt] = mfma16(vf[mt][0], p0, acc[qt][mt]);
        acc[qt][mt] = mfma16(vf[mt][1], p1, acc[qt][mt]);
      }
    }
  }

#pragma unroll
  for (int qt = 0; qt < 4; ++qt) {
    const float inv = 1.0f / l_run[qt];
    const int q = qw + qt * 16 + mr;
    half_t* crow = ctx + ((size_t)(b * Sc) + q) * Ec + h * Dc;
#pragma unroll
    for (int mt = 0; mt < 4; ++mt) {
      h4 pk;
#pragma unroll
      for (int r = 0; r < 4; ++r) pk[r] = (half_t)(acc[qt][mt][r] * inv);
      *(h4*)(crow + mt * 16 + qd * 4) = pk;
    }
  }
}

// ---------------- global-query attention, fused flash-style (one kernel) ----------------
__global__ __launch_bounds__(256) void gq_fused(const half_t* __restrict__ qgh,
                                                const half_t* __restrict__ kgh,
                                                const half_t* __restrict__ vgt,
                                                half_t* __restrict__ ctx) {
  constexpr int PST = 88;
  __shared__ __align__(16) half_t Pl[4][16 * PST];
  const int h = blockIdx.x & 15, b = blockIdx.x >> 4;
  const int tid = threadIdx.x, wv = tid >> 6, lane = tid & 63;
  const int mr = lane & 15, qd = lane >> 4;
  const size_t bh = (size_t)(b * Hc + h);
  const half_t* qb = qgh + bh * Gc * Dc;
  const half_t* kb = kgh + bh * Sc * Dc;
  const half_t* vb = vgt + bh * Dc * Sc;
  half_t* Pw = &Pl[wv][0];

  const int qrow = wv * 16 + mr;
  const h8 qf0 = *(const h8*)(qb + (size_t)qrow * Dc + qd * 8);
  const h8 qf1 = *(const h8*)(qb + (size_t)qrow * Dc + 32 + qd * 8);

  float m_run = -1e30f, l_run = 0.f;
  f4 acc[4] = {};

  for (int t = 0; t < 64; ++t) {
    const int kp0 = t * 64;
    f4 sa[4];
#pragma unroll
    for (int mt = 0; mt < 4; ++mt) {
      const int kp = kp0 + mt * 16 + mr;
      h8 kf0 = *(const h8*)(kb + (size_t)kp * Dc + qd * 8);
      h8 kf1 = *(const h8*)(kb + (size_t)kp * Dc + 32 + qd * 8);
      f4 s = {};
      s = mfma16(kf0, qf0, s);
      s = mfma16(kf1, qf1, s);
      sa[mt] = s;
    }
    float tm = -1e30f;
#pragma unroll
    for (int mt = 0; mt < 4; ++mt)
#pragma unroll
      for (int r = 0; r < 4; ++r) tm = fmaxf(tm, sa[mt][r]);
    tm = fmaxf(tm, __shfl_xor(tm, 16));
    tm = fmaxf(tm, __shfl_xor(tm, 32));
    const float mnew = fmaxf(m_run, tm);
    const float alpha = __expf(m_run - mnew);
    m_run = mnew;
    float psum = 0.0f;
#pragma unroll
    for (int mt = 0; mt < 4; ++mt) {
      h4 pk;
#pragma unroll
      for (int r = 0; r < 4; ++r) {
        const float p = __expf(sa[mt][r] - mnew);
        psum += p;
        pk[r] = (half_t)p;
      }
      *(h4*)(Pw + mr * PST + mt * 16 + qd * 4) = pk;
    }
    psum += __shfl_xor(psum, 16);
    psum += __shfl_xor(psum, 32);
    l_run = l_run * alpha + psum;
#pragma unroll
    for (int mt = 0; mt < 4; ++mt)
#pragma unroll
      for (int r = 0; r < 4; ++r) acc[mt][r] *= alpha;
    const h8 p0 = *(const h8*)(Pw + mr * PST + qd * 8);
    const h8 p1 = *(const h8*)(Pw + mr * PST + 32 + qd * 8);
#pragma unroll
    for (int mt = 0; mt < 4; ++mt) {
      const h8 vf0 = *(const h8*)(vb + (size_t)(mt * 16 + mr) * Sc + kp0 + qd * 8);
      const h8 vf1 = *(const h8*)(vb + (size_t)(mt * 16 + mr) * Sc + kp0 + 32 + qd * 8);
      acc[mt] = mfma16(vf0, p0, acc[mt]);
      acc[mt] = mfma16(vf1, p1, acc[mt]);
    }
  }

  const float inv = 1.0f / l_run;
  const int g = wv * 16 + mr;
  half_t* crow = ctx + ((size_t)(b * Sc) + g) * Ec + h * Dc;
#pragma unroll
  for (int mt = 0; mt < 4; ++mt) {
    h4 pk;
#pragma unroll
    for (int r = 0; r < 4; ++r) pk[r] = (half_t)(acc[mt][r] * inv);
    *(h4*)(crow + mt * 16 + qd * 4) = pk;
  }
}

// ---------------- host launch ----------------

extern "C" void kernel_launch(void* const* d_in, const int* in_sizes, int n_in,
                              void* d_out, int out_size, void* d_ws, size_t ws_size,
                              hipStream_t stream) {
  const float* x   = (const float*)d_in[0];
  const float* Wq  = (const float*)d_in[2];
  const float* bq  = (const float*)d_in[3];
  const float* Wk  = (const float*)d_in[4];
  const float* bk  = (const float*)d_in[5];
  const float* Wv  = (const float*)d_in[6];
  const float* bv  = (const float*)d_in[7];
  const float* Wqg = (const float*)d_in[8];
  const float* bqg = (const float*)d_in[9];
  const float* Wkg = (const float*)d_in[10];
  const float* bkg = (const float*)d_in[11];
  const float* Wvg = (const float*)d_in[12];
  const float* bvg = (const float*)d_in[13];
  const float* Wo  = (const float*)d_in[14];
  const float* bo  = (const float*)d_in[15];
  float* out = (float*)d_out;

  char* ws = (char*)d_ws;
  size_t off = 0;
  auto alloc = [&](size_t bytes) {
    void* p = ws + off;
    off = (off + bytes + 255) & ~(size_t)255;
    return p;
  };
  const size_t BSE2 = (size_t)Bc * Sc * Ec * 2;
  const size_t W2 = (size_t)Ec * Ec * 2;
  half_t* xh   = (half_t*)alloc(BSE2);
  half_t* Wcat = (half_t*)alloc(W2 * 6);   // q,k,v,kg,vg,qg transposed f16
  half_t* WtO  = (half_t*)alloc(W2);
  half_t* qh   = (half_t*)alloc(BSE2);     // (B,H,S,D) scaled
  half_t* kh   = (half_t*)alloc(BSE2);     // (B,H,S,D)
  half_t* vt   = (half_t*)alloc(BSE2);     // (B,H,D,S)
  half_t* kgh  = (half_t*)alloc(BSE2);     // (B,H,S,D)
  half_t* vgt  = (half_t*)alloc(BSE2);     // (B,H,D,S)
  half_t* qgh  = (half_t*)alloc((size_t)Bc * Hc * Gc * Dc * 2);
  half_t* ctx  = (half_t*)alloc(BSE2);
  (void)ws_size; (void)in_sizes; (void)n_in; (void)out_size;

  prep<<<8192 + 7 * 256, 256, 0, stream>>>(x, Wq, Wk, Wv, Wkg, Wvg, Wqg, Wo,
                                           xh, Wcat, WtO);

  gemm_proj<<<dim3(41, 64), 256, 0, stream>>>(xh, Wcat, bq, bk, bv, bkg, bvg, bqg,
                                              qh, kh, vt, kgh, vgt, qgh);

  win_attn<<<Bc * Hc * (Sc / 256), 256, 0, stream>>>(qh, kh, vt, ctx);

  gq_fused<<<Bc * Hc, 256, 0, stream>>>(qgh, kgh, vgt, ctx);

  gemm_out<<<dim3(8, 64), 256, 0, stream>>>(ctx, WtO, bo, out);
}

// Round 7
// 399.801 us; speedup vs baseline: 1.2643x; 1.2391x over previous
//
#include <hip/hip_runtime.h>

typedef _Float16 half_t;
typedef _Float16 h8 __attribute__((ext_vector_type(8)));
typedef _Float16 h4 __attribute__((ext_vector_type(4)));
typedef float f4 __attribute__((ext_vector_type(4)));

#define DEV __device__ __forceinline__

constexpr int Bc = 2, Sc = 4096, Ec = 1024, Hc = 16, Dc = 64, Wc = 256, Gc = 64;
constexpr float QSCALE = 0.125f;     // 1/sqrt(D)
constexpr float NEGV = -1e9f;

DEV f4 mfma16(h8 a, h8 b, f4 c) {
  return __builtin_amdgcn_mfma_f32_16x16x32_f16(a, b, c, 0, 0, 0);
}

DEV void gl_lds16(const half_t* g, half_t* l) {
  __builtin_amdgcn_global_load_lds((const __attribute__((address_space(1))) void*)g,
                                   (__attribute__((address_space(3))) void*)l, 16, 0, 0);
}

// ---------------- prep: x->f16  +  7 weight transposes, one dispatch ----------------
__global__ void prep(const float* __restrict__ x,
                     const float* __restrict__ Wq, const float* __restrict__ Wk,
                     const float* __restrict__ Wv, const float* __restrict__ Wkg,
                     const float* __restrict__ Wvg, const float* __restrict__ Wqg,
                     const float* __restrict__ Wo,
                     half_t* __restrict__ xh, half_t* __restrict__ Wcat,
                     half_t* __restrict__ WtO) {
  __shared__ float tile[64][65];
  const int bx = blockIdx.x;
  if (bx < 8192) {
    int i = bx * 256 + threadIdx.x;
    float4 v = ((const float4*)x)[i];
    h4 o;
    o[0] = (half_t)v.x; o[1] = (half_t)v.y; o[2] = (half_t)v.z; o[3] = (half_t)v.w;
    ((h4*)xh)[i] = o;
    return;
  }
  const int widx = bx - 8192;
  const int y = widx >> 8;         // 0..6: q,k,v,kg,vg,qg,o
  const int xb = widx & 255;
  const float* W = (y == 0) ? Wq : (y == 1) ? Wk : (y == 2) ? Wv :
                   (y == 3) ? Wkg : (y == 4) ? Wvg : (y == 5) ? Wqg : Wo;
  half_t* Wt = (y < 6) ? (Wcat + (size_t)y * Ec * Ec) : WtO;
  const int bxt = xb & 15, byt = xb >> 4;
  const int tx = threadIdx.x & 63, ty = threadIdx.x >> 6;
  const int n0 = bxt * 64, k0 = byt * 64;
#pragma unroll
  for (int i = 0; i < 16; ++i) {
    int k = ty + i * 4;
    tile[k][tx] = W[(size_t)(k0 + k) * Ec + n0 + tx];
  }
  __syncthreads();
#pragma unroll
  for (int i = 0; i < 16; ++i) {
    int n = ty + i * 4;
    Wt[(size_t)(n0 + n) * Ec + k0 + tx] = (half_t)tile[tx][n];
  }
}

// ------ fused projection GEMM, BK=32: xh(8192x1024) @ Wcat(6144x1024)^T ------
// grid (40,65). y<64: g=col/1024: 0=q(BHSD,scale) 1=k(BHSD) 2=v(BHDS) 3=kg(BHSD) 4=vg(BHDS)
// y==64, x<8: qg over 128 gathered rows (s<G per batch), g=5.
// grid.x=40 (mult of 8) -> XCD = col-tile mod 8: B col-tiles stay L2-resident
// (41-wide grid rotated the mapping: FETCH 89->230 MB, R4 vs R6).
__global__ __launch_bounds__(256) void gemm_proj(const half_t* __restrict__ A,
                                                 const half_t* __restrict__ Bt,
                                                 const float* __restrict__ bq,
                                                 const float* __restrict__ bk,
                                                 const float* __restrict__ bv,
                                                 const float* __restrict__ bkg,
                                                 const float* __restrict__ bvg,
                                                 const float* __restrict__ bqg,
                                                 half_t* __restrict__ qh, half_t* __restrict__ kh,
                                                 half_t* __restrict__ vt, half_t* __restrict__ kgh,
                                                 half_t* __restrict__ vgt, half_t* __restrict__ qgh) {
  __shared__ __align__(16) half_t Ash[128 * 32];
  __shared__ __align__(16) half_t Bsh[128 * 32];
  const bool qgblk = (blockIdx.y == 64);
  if (qgblk && blockIdx.x >= 8) return;
  const int tid = threadIdx.x;
  const int wv = tid >> 6, lane = tid & 63;
  const int mr = lane & 15, qd = lane >> 4;
  const int wv_m = wv >> 1, wv_n = wv & 1;
  const int col0 = qgblk ? (5 * Ec + (int)blockIdx.x * 128) : (int)blockIdx.x * 128;
  const int row0 = qgblk ? 0 : (int)blockIdx.y * 128;
  const int g = col0 >> 10;

  f4 acc[4][4] = {};

  for (int k0 = 0; k0 < Ec; k0 += 32) {
#pragma unroll
    for (int i = 0; i < 2; ++i) {
      int slot = wv * 128 + i * 64 + lane;
      int r = slot >> 2;
      int kc = (slot & 3) ^ ((r >> 1) & 3);  // parity-spread swizzle (0 conflicts, R4)
      int ar = qgblk ? ((r < 64) ? r : 4032 + r) : (row0 + r);
      gl_lds16(A + (size_t)ar * Ec + k0 + kc * 8, Ash + (size_t)(wv * 128 + i * 64) * 8);
      gl_lds16(Bt + (size_t)(col0 + r) * Ec + k0 + kc * 8, Bsh + (size_t)(wv * 128 + i * 64) * 8);
    }
    __syncthreads();
    h8 af[4], bf[4];
#pragma unroll
    for (int mt = 0; mt < 4; ++mt) {
      int r = wv_m * 64 + mt * 16 + mr;
      af[mt] = *(const h8*)(Ash + (size_t)((r << 2) | (qd ^ ((r >> 1) & 3))) * 8);
    }
#pragma unroll
    for (int nt = 0; nt < 4; ++nt) {
      int r = wv_n * 64 + nt * 16 + mr;
      bf[nt] = *(const h8*)(Bsh + (size_t)((r << 2) | (qd ^ ((r >> 1) & 3))) * 8);
    }
#pragma unroll
    for (int mt = 0; mt < 4; ++mt)
#pragma unroll
      for (int nt = 0; nt < 4; ++nt)
        acc[mt][nt] = mfma16(af[mt], bf[nt], acc[mt][nt]);
    __syncthreads();
  }

  const float* bptr = (g == 0) ? bq : (g == 1) ? bk : (g == 2) ? bv :
                      (g == 3) ? bkg : (g == 4) ? bvg : bqg;
#pragma unroll
  for (int mt = 0; mt < 4; ++mt) {
#pragma unroll
    for (int nt = 0; nt < 4; ++nt) {
      const int C = col0 + wv_n * 64 + nt * 16 + mr;
      const int c1 = C & 1023, hh = c1 >> 6, d = c1 & 63;
      const float bval = bptr[c1];
      const int Rbase = row0 + wv_m * 64 + mt * 16 + qd * 4;
      f4 a = acc[mt][nt];
      if (g == 2 || g == 4) {  // transposed (B,H,D,S)
        half_t* O = (g == 2) ? vt : vgt;
        int b = Rbase >> 12, s = Rbase & 4095;
        h4 pk;
#pragma unroll
        for (int r = 0; r < 4; ++r) pk[r] = (half_t)(a[r] + bval);
        *(h4*)(O + ((size_t)(b * Hc + hh) * Dc + d) * Sc + s) = pk;
      } else if (g == 5) {     // qg: (B,H,G,D), gathered rows
#pragma unroll
        for (int r = 0; r < 4; ++r) {
          int rr = Rbase + r;
          int b = rr >> 6, s = rr & 63;
          qgh[((size_t)(b * Hc + hh) * Gc + s) * Dc + d] = (half_t)((a[r] + bval) * QSCALE);
        }
      } else {                 // (B,H,S,D), q scaled
        half_t* O = (g == 0) ? qh : (g == 1) ? kh : kgh;
        const float scale = (g == 0) ? QSCALE : 1.0f;
#pragma unroll
        for (int r = 0; r < 4; ++r) {
          int R = Rbase + r;
          int b = R >> 12, s = R & 4095;
          O[((size_t)(b * Hc + hh) * Sc + s) * Dc + d] = (half_t)((a[r] + bval) * scale);
        }
      }
    }
  }
}

// ---------------- output GEMM, BK=32: ctx(8192x1024) @ WtO^T + bo -> fp32 ----------------
__global__ __launch_bounds__(256) void gemm_out(const half_t* __restrict__ A,
                                                const half_t* __restrict__ Bt,
                                                const float* __restrict__ bias,
                                                float* __restrict__ O) {
  __shared__ __align__(16) half_t Ash[128 * 32];
  __shared__ __align__(16) half_t Bsh[128 * 32];
  const int tid = threadIdx.x;
  const int wv = tid >> 6, lane = tid & 63;
  const int mr = lane & 15, qd = lane >> 4;
  const int wv_m = wv >> 1, wv_n = wv & 1;
  const int col0 = blockIdx.x * 128;
  const int row0 = blockIdx.y * 128;

  f4 acc[4][4] = {};

  for (int k0 = 0; k0 < Ec; k0 += 32) {
#pragma unroll
    for (int i = 0; i < 2; ++i) {
      int slot = wv * 128 + i * 64 + lane;
      int r = slot >> 2;
      int kc = (slot & 3) ^ ((r >> 1) & 3);
      gl_lds16(A + (size_t)(row0 + r) * Ec + k0 + kc * 8, Ash + (size_t)(wv * 128 + i * 64) * 8);
      gl_lds16(Bt + (size_t)(col0 + r) * Ec + k0 + kc * 8, Bsh + (size_t)(wv * 128 + i * 64) * 8);
    }
    __syncthreads();
    h8 af[4], bf[4];
#pragma unroll
    for (int mt = 0; mt < 4; ++mt) {
      int r = wv_m * 64 + mt * 16 + mr;
      af[mt] = *(const h8*)(Ash + (size_t)((r << 2) | (qd ^ ((r >> 1) & 3))) * 8);
    }
#pragma unroll
    for (int nt = 0; nt < 4; ++nt) {
      int r = wv_n * 64 + nt * 16 + mr;
      bf[nt] = *(const h8*)(Bsh + (size_t)((r << 2) | (qd ^ ((r >> 1) & 3))) * 8);
    }
#pragma unroll
    for (int mt = 0; mt < 4; ++mt)
#pragma unroll
      for (int nt = 0; nt < 4; ++nt)
        acc[mt][nt] = mfma16(af[mt], bf[nt], acc[mt][nt]);
    __syncthreads();
  }

#pragma unroll
  for (int mt = 0; mt < 4; ++mt) {
#pragma unroll
    for (int nt = 0; nt < 4; ++nt) {
      const int C = col0 + wv_n * 64 + nt * 16 + mr;
      const float bval = bias[C];
      const int Rbase = row0 + wv_m * 64 + mt * 16 + qd * 4;
      f4 a = acc[mt][nt];
#pragma unroll
      for (int r = 0; r < 4; ++r)
        O[(size_t)(Rbase + r) * Ec + C] = a[r] + bval;
    }
  }
}

// ---------------- windowed + global-key attention (flash-style, LDS-staged) ----------------
__global__ __launch_bounds__(256) void win_attn(const half_t* __restrict__ qh,
                                                const half_t* __restrict__ kh,
                                                const half_t* __restrict__ vt,
                                                half_t* __restrict__ ctx) {
  constexpr int PST = 88;
  __shared__ __align__(16) half_t Kb[2][64 * 64];
  __shared__ __align__(16) half_t Vb[2][64 * 64];
  __shared__ __align__(16) half_t Pl[4][16 * PST];
  const int bid = blockIdx.x;
  const int qc = bid & 15, h = (bid >> 4) & 15, b = bid >> 8;
  const int qs = qc << 8;
  const int tid = threadIdx.x, wv = tid >> 6, lane = tid & 63;
  const int mr = lane & 15, qd = lane >> 4;
  const int qw = qs + wv * 64;
  const size_t bh = (size_t)(b * Hc + h);
  const half_t* qb = qh + bh * Sc * Dc;
  const half_t* kb = kh + bh * Sc * Dc;
  const half_t* vb = vt + bh * Dc * Sc;
  half_t* Pw = &Pl[wv][0];

  h8 qf[4][2];
#pragma unroll
  for (int qt = 0; qt < 4; ++qt) {
    const half_t* qrow = qb + (size_t)(qw + qt * 16 + mr) * Dc;
    qf[qt][0] = *(const h8*)(qrow + qd * 8);
    qf[qt][1] = *(const h8*)(qrow + 32 + qd * 8);
  }

  int tiles[14];
  int nT = 0;
  tiles[nT++] = 0;
  {
    int lo = qs - Wc; if (lo < Gc) lo = Gc;
    int hi = qs + 448; if (hi > Sc - 64) hi = Sc - 64;
    for (int kp0 = lo; kp0 <= hi; kp0 += 64) tiles[nT++] = kp0;
  }

  auto stage = [&](int kp0, int bi) {
#pragma unroll
    for (int i = 0; i < 2; ++i) {
      const int seg = wv * 2 + i;
      const int s = seg * 64 + lane;
      const int r = s >> 3;
      const int kc = (s & 7) ^ (r & 7);
      gl_lds16(kb + (size_t)(kp0 + r) * Dc + kc * 8, &Kb[bi][seg * 512]);
      gl_lds16(vb + (size_t)r * Sc + kp0 + kc * 8, &Vb[bi][seg * 512]);
    }
  };

  float m_run[4], l_run[4];
  f4 acc[4][4] = {};
#pragma unroll
  for (int qt = 0; qt < 4; ++qt) { m_run[qt] = -1e30f; l_run[qt] = 0.f; }

  stage(tiles[0], 0);

  for (int t = 0; t < nT; ++t) {
    __syncthreads();
    if (t + 1 < nT) stage(tiles[t + 1], (t + 1) & 1);
    const int kp0 = tiles[t];
    if (t > 0 && (kp0 > qw + 319 || kp0 + 63 < qw - Wc)) continue;

    const half_t* BK = Kb[t & 1];
    const half_t* BV = Vb[t & 1];
    h8 kf[4][2], vf[4][2];
#pragma unroll
    for (int mt = 0; mt < 4; ++mt) {
      const int row = mt * 16 + mr, r7 = row & 7;
      kf[mt][0] = *(const h8*)(BK + (size_t)(row * 8 + (qd ^ r7)) * 8);
      kf[mt][1] = *(const h8*)(BK + (size_t)(row * 8 + ((qd + 4) ^ r7)) * 8);
      vf[mt][0] = *(const h8*)(BV + (size_t)(row * 8 + (qd ^ r7)) * 8);
      vf[mt][1] = *(const h8*)(BV + (size_t)(row * 8 + ((qd + 4) ^ r7)) * 8);
    }
    const bool nomask = (t == 0) || (kp0 >= qw - 193 && kp0 <= qw + 193);

#pragma unroll
    for (int qt = 0; qt < 4; ++qt) {
      f4 sa[4];
#pragma unroll
      for (int mt = 0; mt < 4; ++mt) {
        f4 s = {};
        s = mfma16(kf[mt][0], qf[qt][0], s);
        s = mfma16(kf[mt][1], qf[qt][1], s);
        sa[mt] = s;
      }
      const int q = qw + qt * 16 + mr;
      if (!nomask) {
#pragma unroll
        for (int mt = 0; mt < 4; ++mt)
#pragma unroll
          for (int r = 0; r < 4; ++r) {
            const int kp = kp0 + mt * 16 + qd * 4 + r;
            if (kp < q - Wc || kp > q + Wc) sa[mt][r] = NEGV;
          }
      }
      float tm = -1e30f;
#pragma unroll
      for (int mt = 0; mt < 4; ++mt)
#pragma unroll
        for (int r = 0; r < 4; ++r) tm = fmaxf(tm, sa[mt][r]);
      tm = fmaxf(tm, __shfl_xor(tm, 16));
      tm = fmaxf(tm, __shfl_xor(tm, 32));
      const float mnew = fmaxf(m_run[qt], tm);
      const float alpha = __expf(m_run[qt] - mnew);
      m_run[qt] = mnew;
      float psum = 0.0f;
#pragma unroll
      for (int mt = 0; mt < 4; ++mt) {
        h4 pk;
#pragma unroll
        for (int r = 0; r < 4; ++r) {
          const float p = __expf(sa[mt][r] - mnew);
          psum += p;
          pk[r] = (half_t)p;
        }
        *(h4*)(Pw + mr * PST + mt * 16 + qd * 4) = pk;
      }
      psum += __shfl_xor(psum, 16);
      psum += __shfl_xor(psum, 32);
      l_run[qt] = l_run[qt] * alpha + psum;
#pragma unroll
      for (int mt = 0; mt < 4; ++mt)
#pragma unroll
        for (int r = 0; r < 4; ++r) acc[qt][mt][r] *= alpha;
      const h8 p0 = *(const h8*)(Pw + mr * PST + qd * 8);
      const h8 p1 = *(const h8*)(Pw + mr * PST + 32 + qd * 8);
#pragma unroll
      for (int mt = 0; mt < 4; ++mt) {
        acc[qt][mt] = mfma16(vf[mt][0], p0, acc[qt][mt]);
        acc[qt][mt] = mfma16(vf[mt][1], p1, acc[qt][mt]);
      }
    }
  }

#pragma unroll
  for (int qt = 0; qt < 4; ++qt) {
    const float inv = 1.0f / l_run[qt];
    const int q = qw + qt * 16 + mr;
    half_t* crow = ctx + ((size_t)(b * Sc) + q) * Ec + h * Dc;
#pragma unroll
    for (int mt = 0; mt < 4; ++mt) {
      h4 pk;
#pragma unroll
      for (int r = 0; r < 4; ++r) pk[r] = (half_t)(acc[qt][mt][r] * inv);
      *(h4*)(crow + mt * 16 + qd * 4) = pk;
    }
  }
}

// ---------------- global-query attention: flash-decoding split over S ----------------
// gq_part: grid = B*H*8; each block: 512 keys (8 tiles), partial m/l/O^T to ws.
__global__ __launch_bounds__(256) void gq_part(const half_t* __restrict__ qgh,
                                               const half_t* __restrict__ kgh,
                                               const half_t* __restrict__ vgt,
                                               float* __restrict__ pm,
                                               float* __restrict__ pl,
                                               float* __restrict__ pacc) {
  constexpr int PST = 88;
  __shared__ __align__(16) half_t Pl[4][16 * PST];
  const int ch = blockIdx.x & 7, h = (blockIdx.x >> 3) & 15, b = blockIdx.x >> 7;
  const int tid = threadIdx.x, wv = tid >> 6, lane = tid & 63;
  const int mr = lane & 15, qd = lane >> 4;
  const size_t bh = (size_t)(b * Hc + h);
  const half_t* qb = qgh + bh * Gc * Dc;
  const half_t* kb = kgh + bh * Sc * Dc;
  const half_t* vb = vgt + bh * Dc * Sc;
  half_t* Pw = &Pl[wv][0];

  const int qrow = wv * 16 + mr;
  const h8 qf0 = *(const h8*)(qb + (size_t)qrow * Dc + qd * 8);
  const h8 qf1 = *(const h8*)(qb + (size_t)qrow * Dc + 32 + qd * 8);

  float m_run = -1e30f, l_run = 0.f;
  f4 acc[4] = {};

  for (int t = 0; t < 8; ++t) {
    const int kp0 = ch * 512 + t * 64;
    f4 sa[4];
#pragma unroll
    for (int mt = 0; mt < 4; ++mt) {
      const int kp = kp0 + mt * 16 + mr;
      h8 kf0 = *(const h8*)(kb + (size_t)kp * Dc + qd * 8);
      h8 kf1 = *(const h8*)(kb + (size_t)kp * Dc + 32 + qd * 8);
      f4 s = {};
      s = mfma16(kf0, qf0, s);
      s = mfma16(kf1, qf1, s);
      sa[mt] = s;
    }
    float tm = -1e30f;
#pragma unroll
    for (int mt = 0; mt < 4; ++mt)
#pragma unroll
      for (int r = 0; r < 4; ++r) tm = fmaxf(tm, sa[mt][r]);
    tm = fmaxf(tm, __shfl_xor(tm, 16));
    tm = fmaxf(tm, __shfl_xor(tm, 32));
    const float mnew = fmaxf(m_run, tm);
    const float alpha = __expf(m_run - mnew);
    m_run = mnew;
    float psum = 0.0f;
#pragma unroll
    for (int mt = 0; mt < 4; ++mt) {
      h4 pk;
#pragma unroll
      for (int r = 0; r < 4; ++r) {
        const float p = __expf(sa[mt][r] - mnew);
        psum += p;
        pk[r] = (half_t)p;
      }
      *(h4*)(Pw + mr * PST + mt * 16 + qd * 4) = pk;
    }
    psum += __shfl_xor(psum, 16);
    psum += __shfl_xor(psum, 32);
    l_run = l_run * alpha + psum;
#pragma unroll
    for (int mt = 0; mt < 4; ++mt)
#pragma unroll
      for (int r = 0; r < 4; ++r) acc[mt][r] *= alpha;
    const h8 p0 = *(const h8*)(Pw + mr * PST + qd * 8);
    const h8 p1 = *(const h8*)(Pw + mr * PST + 32 + qd * 8);
#pragma unroll
    for (int mt = 0; mt < 4; ++mt) {
      const h8 vf0 = *(const h8*)(vb + (size_t)(mt * 16 + mr) * Sc + kp0 + qd * 8);
      const h8 vf1 = *(const h8*)(vb + (size_t)(mt * 16 + mr) * Sc + kp0 + 32 + qd * 8);
      acc[mt] = mfma16(vf0, p0, acc[mt]);
      acc[mt] = mfma16(vf1, p1, acc[mt]);
    }
  }

  const size_t pidx = (bh * 8 + ch) * Gc + qrow;
  if (qd == 0) { pm[pidx] = m_run; pl[pidx] = l_run; }
  float* pa = pacc + pidx * Dc;
#pragma unroll
  for (int mt = 0; mt < 4; ++mt)
#pragma unroll
    for (int r = 0; r < 4; ++r)
      pa[mt * 16 + qd * 4 + r] = acc[mt][r];
}

// gq_combine: grid = B*H; thread (q = tid>>2, 16 d's at dg=(tid&3)*16) merges 8 chunks.
__global__ __launch_bounds__(256) void gq_combine(const float* __restrict__ pm,
                                                  const float* __restrict__ pl,
                                                  const float* __restrict__ pacc,
                                                  half_t* __restrict__ ctx) {
  const int h = blockIdx.x & 15, b = blockIdx.x >> 4;
  const size_t bh = (size_t)(b * Hc + h);
  const int q = threadIdx.x >> 2, dg = (threadIdx.x & 3) * 16;
  float m[8];
  float M = -1e30f;
#pragma unroll
  for (int c = 0; c < 8; ++c) {
    m[c] = pm[(bh * 8 + c) * Gc + q];
    M = fmaxf(M, m[c]);
  }
  float denom = 0.f, num[16] = {};
#pragma unroll
  for (int c = 0; c < 8; ++c) {
    const float w = __expf(m[c] - M);
    denom += w * pl[(bh * 8 + c) * Gc + q];
    const float* pa = pacc + ((bh * 8 + c) * Gc + q) * Dc + dg;
#pragma unroll
    for (int j = 0; j < 16; ++j) num[j] += w * pa[j];
  }
  const float inv = 1.0f / denom;
  half_t* crow = ctx + ((size_t)(b * Sc) + q) * Ec + h * Dc + dg;
#pragma unroll
  for (int j = 0; j < 16; ++j) crow[j] = (half_t)(num[j] * inv);
}

// ---------------- host launch ----------------

extern "C" void kernel_launch(void* const* d_in, const int* in_sizes, int n_in,
                              void* d_out, int out_size, void* d_ws, size_t ws_size,
                              hipStream_t stream) {
  const float* x   = (const float*)d_in[0];
  const float* Wq  = (const float*)d_in[2];
  const float* bq  = (const float*)d_in[3];
  const float* Wk  = (const float*)d_in[4];
  const float* bk  = (const float*)d_in[5];
  const float* Wv  = (const float*)d_in[6];
  const float* bv  = (const float*)d_in[7];
  const float* Wqg = (const float*)d_in[8];
  const float* bqg = (const float*)d_in[9];
  const float* Wkg = (const float*)d_in[10];
  const float* bkg = (const float*)d_in[11];
  const float* Wvg = (const float*)d_in[12];
  const float* bvg = (const float*)d_in[13];
  const float* Wo  = (const float*)d_in[14];
  const float* bo  = (const float*)d_in[15];
  float* out = (float*)d_out;

  char* ws = (char*)d_ws;
  size_t off = 0;
  auto alloc = [&](size_t bytes) {
    void* p = ws + off;
    off = (off + bytes + 255) & ~(size_t)255;
    return p;
  };
  const size_t BSE2 = (size_t)Bc * Sc * Ec * 2;
  const size_t W2 = (size_t)Ec * Ec * 2;
  half_t* xh   = (half_t*)alloc(BSE2);
  half_t* Wcat = (half_t*)alloc(W2 * 6);   // q,k,v,kg,vg,qg transposed f16
  half_t* WtO  = (half_t*)alloc(W2);
  half_t* qh   = (half_t*)alloc(BSE2);     // (B,H,S,D) scaled
  half_t* kh   = (half_t*)alloc(BSE2);     // (B,H,S,D)
  half_t* vt   = (half_t*)alloc(BSE2);     // (B,H,D,S)
  half_t* kgh  = (half_t*)alloc(BSE2);     // (B,H,S,D)
  half_t* vgt  = (half_t*)alloc(BSE2);     // (B,H,D,S)
  half_t* qgh  = (half_t*)alloc((size_t)Bc * Hc * Gc * Dc * 2);
  half_t* ctx  = (half_t*)alloc(BSE2);
  float*  pm   = (float*)alloc((size_t)Bc * Hc * 8 * Gc * 4);
  float*  pl   = (float*)alloc((size_t)Bc * Hc * 8 * Gc * 4);
  float*  pacc = (float*)alloc((size_t)Bc * Hc * 8 * Gc * Dc * 4);
  (void)ws_size; (void)in_sizes; (void)n_in; (void)out_size;

  prep<<<8192 + 7 * 256, 256, 0, stream>>>(x, Wq, Wk, Wv, Wkg, Wvg, Wqg, Wo,
                                           xh, Wcat, WtO);

  gemm_proj<<<dim3(40, 65), 256, 0, stream>>>(xh, Wcat, bq, bk, bv, bkg, bvg, bqg,
                                              qh, kh, vt, kgh, vgt, qgh);

  win_attn<<<Bc * Hc * (Sc / 256), 256, 0, stream>>>(qh, kh, vt, ctx);

  gq_part<<<Bc * Hc * 8, 256, 0, stream>>>(qgh, kgh, vgt, pm, pl, pacc);
  gq_combine<<<Bc * Hc, 256, 0, stream>>>(pm, pl, pacc, ctx);

  gemm_out<<<dim3(8, 64), 256, 0, stream>>>(ctx, WtO, bo, out);
}